// Round 4
// baseline (149.206 us; speedup 1.0000x reference)
//
#include <hip/hip_runtime.h>
#include <hip/hip_bf16.h>
#include <stdint.h>

#define BB   8
#define NN   4096
#define FIN  32
#define FF   33          // FIN + 1 noise channel
#define KPAD 64          // pad feature dim to 2 MFMA k-steps
#define NQ   (BB*NN)     // 32768 query points
#define THR  27.0f       // d2 threshold: exp(-27)=1.9e-12; survivors/query ~ Poisson(4)
#define CAP  16
#define NTRI 136         // 16*17/2 slab pairs (qt <= ms), 256-row slabs
#define INF_IDX 0x7FFFFFFF

// workspace layout (bytes) — fast path, ~6.6 MB total
#define OFF_FB16   0ull
#define OFF_SQ     (OFF_FB16 + (size_t)NQ*KPAD*2)     // 4 MB
#define OFF_CNT    (OFF_SQ   + (size_t)NQ*4)
#define OFF_LISTS  (OFF_CNT  + (size_t)NQ*4)
#define OFF_PART   (OFF_LISTS + (size_t)NQ*CAP*4)     // +2 MB
#define WS_NEED    (OFF_PART + (size_t)(NQ/4)*4)

typedef short short8 __attribute__((ext_vector_type(8)));
typedef float floatx4 __attribute__((ext_vector_type(4)));

// ---------------- prep: f = [x, noise] -> bf16 padded rows + fp32 sq; zero cnt ----------------
__global__ __launch_bounds__(256) void prep_kernel(const float* __restrict__ x,
                                                   const float* __restrict__ noise,
                                                   unsigned short* __restrict__ fb,
                                                   float* __restrict__ sqv,
                                                   int* __restrict__ cnt) {
    int q = blockIdx.x * 256 + threadIdx.x;
    if (q >= NQ) return;
    cnt[q] = 0;
    const float* xr = x + (size_t)q * FIN;
    float v[FF];
#pragma unroll
    for (int d = 0; d < FIN; ++d) v[d] = xr[d];
    v[FIN] = noise[q];
    float s = 0.f;
#pragma unroll
    for (int d = 0; d < FF; ++d) s += v[d] * v[d];
    sqv[q] = s;
    unsigned short row[KPAD];
#pragma unroll
    for (int d = 0; d < FF; ++d) {
        __hip_bfloat16 h = __float2bfloat16(v[d]);
        row[d] = *(unsigned short*)&h;
    }
#pragma unroll
    for (int d = FF; d < KPAD; ++d) row[d] = 0;
    uint4* dst = (uint4*)(fb + (size_t)q * KPAD);
    const uint4* src = (const uint4*)row;
#pragma unroll
    for (int i = 0; i < 8; ++i) dst[i] = src[i];
}

// ---------------- phase 1: symmetric MFMA sieve, LDS double-buffered B ----------------
// Triangle block (bb, qt<=ms): q-slab = 256 rows [qt*256,..), m-slab = [ms*256,..).
// Wave w owns 64 q rows; waves 2,3 stage the shared 16-row B-tile into LDS (dbuf).
// Hit iff d2 = sq_n + sq_m - 2*dot < THR, recorded for BOTH n and m (m>n evaluated once).
__global__ __launch_bounds__(256) void knn_kernel(const unsigned short* __restrict__ fb,
                                                  const float* __restrict__ sqv,
                                                  int* __restrict__ cnt,
                                                  int* __restrict__ lists) {
    __shared__ uint4 lbuf[2][128];   // 2 x 2KB: 16 rows x 64 bf16, fragment-ordered
    int bb  = blockIdx.x / NTRI;
    int tri = blockIdx.x % NTRI;
    int t = tri, qt = 0;
    while (t >= 16 - qt) { t -= 16 - qt; ++qt; }
    int ms = qt + t;

    int wid = threadIdx.x >> 6, lane = threadIdx.x & 63;
    int qb  = qt * 256 + wid * 64;     // wave's query base (within batch)
    int g16 = lane >> 4, l16 = lane & 15;
    size_t base = (size_t)bb * NN;
    int mstart = ms * 256;

    // A fragments (4 tiles of 16 rows) + negated row thresholds folded for MFMA C-init
    short8 a0[4], a1[4];
    floatx4 tneg[4];
#pragma unroll
    for (int a = 0; a < 4; ++a) {
        const short8* fA = (const short8*)(fb + (base + qb + a * 16 + l16) * KPAD + g16 * 8);
        a0[a] = fA[0];
        a1[a] = fA[4];   // k += 32
#pragma unroll
        for (int r = 0; r < 4; ++r)
            tneg[a][r] = 0.5f * THR - 0.5f * sqv[base + qb + a * 16 + g16 * 4 + r];
    }

    // staging lanes: waves 2,3 (they skip the most diagonal-tile compute)
    bool stager = (wid >= 2);
    int  swid   = wid - 2;
    const uint4* gB = (const uint4*)fb + (base + (size_t)mstart) * (KPAD / 8);
    int sidx = (lane & 15) * (KPAD / 8) + (lane >> 4) + (swid << 2);  // row*8 + kchunk

    if (stager) lbuf[0][(swid << 6) + lane] = gB[sidx];   // prologue: tile 0 -> buf 0
    __syncthreads();

    for (int mt = 0; mt < 16; ++mt) {
        int cur = mt & 1;
        uint4 st;
        bool havenext = stager && (mt + 1 < 16);
        if (havenext) st = gB[(mt + 1) * 128 + sidx];     // issue early (T14 split)

        int mb = mstart + mt * 16;
        if (mb + 16 > qb) {                               // skip all-below-diagonal tiles
            const short8* lb = (const short8*)lbuf[cur];
            short8 b0 = lb[lane];
            short8 b1 = lb[64 + lane];
            float hc = 0.5f * sqv[base + mb + l16];       // C/D col = lane&15
#pragma unroll
            for (int a = 0; a < 4; ++a) {
                floatx4 acc = tneg[a];
                acc = __builtin_amdgcn_mfma_f32_16x16x32_bf16(a0[a], b0, acc, 0, 0, 0);
                acc = __builtin_amdgcn_mfma_f32_16x16x32_bf16(a1[a], b1, acc, 0, 0, 0);
                float mm = fmaxf(fmaxf(acc[0], acc[1]), fmaxf(acc[2], acc[3]));
                if (mm > hc) {                            // some row hit: dot-t > hc <=> d2 < THR
                    int m = mb + l16;
#pragma unroll
                    for (int r = 0; r < 4; ++r) {
                        int n = qb + a * 16 + g16 * 4 + r;  // C/D row = (lane>>4)*4 + reg
                        if (acc[r] > hc && m > n) {
                            int p1 = atomicAdd(&cnt[base + n], 1);
                            if (p1 < CAP) lists[(base + n) * CAP + p1] = m;
                            int p2 = atomicAdd(&cnt[base + m], 1);
                            if (p2 < CAP) lists[(base + m) * CAP + p2] = n;
                        }
                    }
                }
            }
        }
        if (havenext) lbuf[cur ^ 1][(swid << 6) + lane] = st;  // write-late after compute
        __syncthreads();
    }
}

// ---------------- shared head: [f, md] @ W1 + b1, relu, out, mse partial ----------------
__device__ inline void head_epilogue(int wid, int lane, int q, float fnd, float md,
                                     const float* __restrict__ y,
                                     const float* __restrict__ W1,
                                     const float* __restrict__ b1,
                                     float* __restrict__ out,
                                     float* __restrict__ partials,
                                     float (*e_lds)[2 * FF], float* msep) {
    if (lane < FF) {
        e_lds[wid][lane]      = fnd;
        e_lds[wid][FF + lane] = md;
    }
    __syncthreads();
    float g = 0.f;
    if (lane < FIN) {
        g = b1[lane];
#pragma unroll
        for (int e = 0; e < 2 * FF; ++e)
            g = fmaf(e_lds[wid][e], W1[e * FIN + lane], g);
        g = fmaxf(g, 0.f);
        out[(size_t)q * FIN + lane] = g;
    }
    float d = 0.f;
    if (lane < FIN) {
        float t = g - y[(size_t)q * FIN + lane];
        d = t * t;
    }
#pragma unroll
    for (int off = 32; off; off >>= 1) d += __shfl_xor(d, off);
    if (lane == 0) msep[wid] = d;
    __syncthreads();
    if (threadIdx.x == 0)
        partials[blockIdx.x] = msep[0] + msep[1] + msep[2] + msep[3];
}

// ---------------- phase 2 (fast): exact fp32 weights over survivors; self explicit ----------------
__global__ __launch_bounds__(256) void gather_kernel(const float* __restrict__ x,
                                                     const float* __restrict__ noise,
                                                     const float* __restrict__ y,
                                                     const float* __restrict__ W1,
                                                     const float* __restrict__ b1,
                                                     const int* __restrict__ cnt,
                                                     const int* __restrict__ lists,
                                                     float* __restrict__ out,
                                                     float* __restrict__ partials) {
    __shared__ float e_lds[4][2 * FF];
    __shared__ float msep[4];
    int wid = threadIdx.x >> 6, lane = threadIdx.x & 63;
    int q = blockIdx.x * 4 + wid;
    int bb = q >> 12;
    int nloc = q & (NN - 1);
    size_t base = (size_t)bb * NN;

    float fnd = 0.f;
    if (lane < FIN)          fnd = x[(size_t)q * FIN + lane];
    else if (lane == FF - 1) fnd = noise[q];

    int c = cnt[q];
    if (c > CAP) c = CAP;
    int mj = (lane < c) ? lists[(size_t)q * CAP + lane] : INF_IDX;
    if (mj == nloc) mj = INF_IDX;   // self handled explicitly

    float den = 1.f, num = 0.f;     // self: w=1 (s==0 exactly), diff==0
    for (int it = 0; it < c; ++it) {
        int v = mj;                 // extract smallest remaining index (deterministic order)
#pragma unroll
        for (int off = 32; off; off >>= 1) {
            int o = __shfl_xor(v, off);
            v = v < o ? v : o;
        }
        if (v == INF_IDX) break;
        if (mj == v) mj = INF_IDX;
        int m = v;
        float fmd = 0.f;
        if (lane < FIN)          fmd = x[(base + m) * (size_t)FIN + lane];
        else if (lane == FF - 1) fmd = noise[base + m];
        float diff = (lane < FF) ? (fmd - fnd) : 0.f;
        float s = diff * diff;
#pragma unroll
        for (int off = 32; off; off >>= 1) s += __shfl_xor(s, off);
        float w = __expf(-s);       // exact fp32 d2: garbage survivors -> w ~ e^-60 ~ 0
        den += w;
        num += w * diff;
    }
    float md = num / den;           // den >= 1 always

    head_epilogue(wid, lane, q, fnd, md, y, W1, b1, out, partials, e_lds, msep);
}

// ---------------- phase 2 (fallback, ws too small): brute-force exact scan ----------------
__global__ __launch_bounds__(256) void gather_brute(const float* __restrict__ x,
                                                    const float* __restrict__ noise,
                                                    const float* __restrict__ y,
                                                    const float* __restrict__ W1,
                                                    const float* __restrict__ b1,
                                                    float* __restrict__ out,
                                                    float* __restrict__ partials) {
    __shared__ float e_lds[4][2 * FF];
    __shared__ float msep[4];
    int wid = threadIdx.x >> 6, lane = threadIdx.x & 63;
    int q = blockIdx.x * 4 + wid;
    int bb = q >> 12;
    int nloc = q & (NN - 1);
    size_t base = (size_t)bb * NN;

    float fnd = 0.f;
    if (lane < FIN)          fnd = x[(size_t)q * FIN + lane];
    else if (lane == FF - 1) fnd = noise[q];

    float den = 1.f, num = 0.f;
    for (int m = 0; m < NN; ++m) {
        if (m == nloc) continue;
        float fmd = 0.f;
        if (lane < FIN)          fmd = x[(base + m) * (size_t)FIN + lane];
        else if (lane == FF - 1) fmd = noise[base + m];
        float diff = (lane < FF) ? (fmd - fnd) : 0.f;
        float s = diff * diff;
#pragma unroll
        for (int off = 32; off; off >>= 1) s += __shfl_xor(s, off);
        float w = __expf(-s);
        den += w;
        num += w * diff;
    }
    float md = num / den;

    head_epilogue(wid, lane, q, fnd, md, y, W1, b1, out, partials, e_lds, msep);
}

// ---------------- final: gen_mse (vectorized) ----------------
__global__ __launch_bounds__(256) void reduce_kernel(const float* __restrict__ partials,
                                                     float* __restrict__ out) {
    __shared__ float sw[4];
    int wid = threadIdx.x >> 6, lane = threadIdx.x & 63;
    const float4* p4 = (const float4*)partials;
    float ax = 0.f, ay = 0.f, az = 0.f, aw = 0.f;
#pragma unroll
    for (int i = threadIdx.x; i < (NQ / 4) / 4; i += 256) {
        float4 v = p4[i];
        ax += v.x; ay += v.y; az += v.z; aw += v.w;
    }
    float a = (ax + ay) + (az + aw);
#pragma unroll
    for (int off = 32; off; off >>= 1) a += __shfl_xor(a, off);
    if (lane == 0) sw[wid] = a;
    __syncthreads();
    if (threadIdx.x == 0)
        out[(size_t)NQ * FIN] = (sw[0] + sw[1] + sw[2] + sw[3]) / (float)((size_t)NQ * FIN);
}

extern "C" void kernel_launch(void* const* d_in, const int* in_sizes, int n_in,
                              void* d_out, int out_size, void* d_ws, size_t ws_size,
                              hipStream_t stream) {
    const float* x     = (const float*)d_in[0];
    const float* noise = (const float*)d_in[1];
    const float* y     = (const float*)d_in[2];
    const float* W1    = (const float*)d_in[3];
    const float* b1    = (const float*)d_in[4];
    float* out = (float*)d_out;
    char* ws = (char*)d_ws;

    if (ws_size >= WS_NEED) {
        unsigned short* fb = (unsigned short*)(ws + OFF_FB16);
        float* sqv     = (float*)(ws + OFF_SQ);
        int*   cnt     = (int*)(ws + OFF_CNT);
        int*   lists   = (int*)(ws + OFF_LISTS);
        float* partial = (float*)(ws + OFF_PART);

        prep_kernel<<<NQ / 256, 256, 0, stream>>>(x, noise, fb, sqv, cnt);
        knn_kernel<<<BB * NTRI, 256, 0, stream>>>(fb, sqv, cnt, lists);
        gather_kernel<<<NQ / 4, 256, 0, stream>>>(x, noise, y, W1, b1, cnt, lists, out, partial);
        reduce_kernel<<<1, 256, 0, stream>>>(partial, out);
    } else {
        // brute-force exact path: needs only 32 KB of scratch for MSE partials
        float* partial = (float*)ws;
        gather_brute<<<NQ / 4, 256, 0, stream>>>(x, noise, y, W1, b1, out, partial);
        reduce_kernel<<<1, 256, 0, stream>>>(partial, out);
    }
}

// Round 5
// 138.305 us; speedup vs baseline: 1.0788x; 1.0788x over previous
//
#include <hip/hip_runtime.h>
#include <hip/hip_bf16.h>
#include <stdint.h>

#define BB   8
#define NN   4096
#define FIN  32
#define FF   33          // FIN + 1 noise channel
#define KPAD 64          // feature dim padded; dims 33,34 carry the threshold fold
#define NQ   (BB*NN)     // 32768 query points
#define CAP  16
#define NTRI 136         // 16*17/2 slab pairs (qt <= ms), 256-row q-slabs
#define INF_IDX 0x7FFFFFFF

// Augmentation: fbA[33]=6.75-sq/2, fbA[34]=1 ; fbB[33]=1, fbB[34]=6.75-sq/2
// => acc = dot - 0.5*sq_n - 0.5*sq_m + 13.5 ;  acc > 0  <=>  d2 < 27

// workspace layout (bytes) — fast path, ~10.2 MB total
#define OFF_FBA    0ull
#define OFF_FBB    (OFF_FBA + (size_t)NQ*KPAD*2)      // 4 MB
#define OFF_CNT    (OFF_FBB + (size_t)NQ*KPAD*2)      // +4 MB
#define OFF_LISTS  (OFF_CNT  + (size_t)NQ*4)
#define OFF_PART   (OFF_LISTS + (size_t)NQ*CAP*4)     // +2 MB
#define WS_NEED    (OFF_PART + (size_t)(NQ/4)*4)

typedef short short8 __attribute__((ext_vector_type(8)));
typedef float floatx4 __attribute__((ext_vector_type(4)));

// ---------------- prep: f=[x,noise] -> two augmented bf16 arrays; zero cnt ----------------
__global__ __launch_bounds__(64) void prep_kernel(const float* __restrict__ x,
                                                  const float* __restrict__ noise,
                                                  unsigned short* __restrict__ fbA,
                                                  unsigned short* __restrict__ fbB,
                                                  int* __restrict__ cnt) {
    int q = blockIdx.x * 64 + threadIdx.x;
    cnt[q] = 0;
    const float4* xr = (const float4*)(x + (size_t)q * FIN);
    float v[FF];
#pragma unroll
    for (int i = 0; i < 8; ++i) {
        float4 t = xr[i];
        v[i*4+0] = t.x; v[i*4+1] = t.y; v[i*4+2] = t.z; v[i*4+3] = t.w;
    }
    v[32] = noise[q];
    float s = 0.f;
#pragma unroll
    for (int d = 0; d < FF; ++d) s += v[d] * v[d];
    unsigned short rowA[KPAD], rowB[KPAD];
#pragma unroll
    for (int d = 0; d < FF; ++d) {
        __hip_bfloat16 h = __float2bfloat16(v[d]);
        unsigned short u = *(unsigned short*)&h;
        rowA[d] = u; rowB[d] = u;
    }
    __hip_bfloat16 hs = __float2bfloat16(6.75f - 0.5f * s);
    unsigned short us = *(unsigned short*)&hs;
    const unsigned short one = 0x3F80;   // bf16 1.0
    rowA[33] = us;  rowA[34] = one;
    rowB[33] = one; rowB[34] = us;
#pragma unroll
    for (int d = 35; d < KPAD; ++d) { rowA[d] = 0; rowB[d] = 0; }
    uint4* dA = (uint4*)(fbA + (size_t)q * KPAD);
    uint4* dB = (uint4*)(fbB + (size_t)q * KPAD);
#pragma unroll
    for (int i = 0; i < 8; ++i) { dA[i] = ((const uint4*)rowA)[i]; dB[i] = ((const uint4*)rowB)[i]; }
}

// ---------------- phase 1: symmetric MFMA sieve, barrier-free, register-prefetched ----------------
// Triangle block (bb, qt<=ms, msub): q-slab = 256 rows, m-range = 128 rows (8 tiles of 16).
// Wave w owns 64 q rows (4 A-tiles), loops m-tiles with next-tile register prefetch.
// Hit iff acc>0 (threshold folded into dims 33/34); recorded for BOTH n and m (m>n once).
__global__ __launch_bounds__(256, 6) void knn_kernel(const unsigned short* __restrict__ fbA,
                                                     const unsigned short* __restrict__ fbB,
                                                     int* __restrict__ cnt,
                                                     int* __restrict__ lists) {
    const int bpb = NTRI * 2;            // 272 blocks per batch
    int bb  = blockIdx.x / bpb;
    int rem = blockIdx.x % bpb;
    int tri = rem >> 1, msub = rem & 1;
    int t = tri, qt = 0;
    while (t >= 16 - qt) { t -= 16 - qt; ++qt; }
    int ms = qt + t;

    int wid = threadIdx.x >> 6, lane = threadIdx.x & 63;
    int qb  = qt * 256 + wid * 64;       // wave's query base (batch-local)
    int g16 = lane >> 4, l16 = lane & 15;
    size_t base = (size_t)bb * NN;
    int mstart = ms * 256 + msub * 128;

    // A fragments: 4 tiles of 16 q-rows (held for all 8 m-tiles)
    short8 a0[4], a1[4];
#pragma unroll
    for (int a = 0; a < 4; ++a) {
        const short8* pA = (const short8*)fbA + ((base + qb + a * 16 + l16) * 8 + g16);
        a0[a] = pA[0];
        a1[a] = pA[4];   // k += 32
    }

    const short8* pB = (const short8*)fbB + ((base + mstart + l16) * 8 + g16);
    short8 b0 = pB[0], b1 = pB[4];       // tile 0

    for (int mt = 0; mt < 8; ++mt) {
        short8 n0, n1;
        if (mt < 7) {                    // issue next-tile loads before current compute
            n0 = pB[(mt + 1) * 128];
            n1 = pB[(mt + 1) * 128 + 4];
        }
        int mb = mstart + mt * 16;
        if (mb + 16 > qb) {              // skip tiles fully below the wave's diagonal
            int m = mb + l16;
#pragma unroll
            for (int a = 0; a < 4; ++a) {
                floatx4 acc = {0.f, 0.f, 0.f, 0.f};
                acc = __builtin_amdgcn_mfma_f32_16x16x32_bf16(a0[a], b0, acc, 0, 0, 0);
                acc = __builtin_amdgcn_mfma_f32_16x16x32_bf16(a1[a], b1, acc, 0, 0, 0);
                float mm = fmaxf(fmaxf(acc[0], acc[1]), fmaxf(acc[2], acc[3]));
                if (mm > 0.f) {
#pragma unroll
                    for (int r = 0; r < 4; ++r) {
                        int n = qb + a * 16 + g16 * 4 + r;   // C/D row = (lane>>4)*4 + reg
                        if (acc[r] > 0.f && m > n) {
                            int p1 = atomicAdd(&cnt[base + n], 1);
                            if (p1 < CAP) lists[(base + n) * CAP + p1] = m;
                            int p2 = atomicAdd(&cnt[base + m], 1);
                            if (p2 < CAP) lists[(base + m) * CAP + p2] = n;
                        }
                    }
                }
            }
        }
        b0 = n0; b1 = n1;                // rotate prefetch (dead on last iter)
    }
}

// ---------------- shared head: [f, md] @ W1 + b1, relu, out, mse partial ----------------
__device__ inline void head_epilogue(int wid, int lane, int q, float fnd, float md,
                                     const float* __restrict__ y,
                                     const float* __restrict__ W1,
                                     const float* __restrict__ b1,
                                     float* __restrict__ out,
                                     float* __restrict__ partials,
                                     float (*e_lds)[2 * FF], float* msep) {
    if (lane < FF) {
        e_lds[wid][lane]      = fnd;
        e_lds[wid][FF + lane] = md;
    }
    __syncthreads();
    float g = 0.f;
    if (lane < FIN) {
        g = b1[lane];
#pragma unroll
        for (int e = 0; e < 2 * FF; ++e)
            g = fmaf(e_lds[wid][e], W1[e * FIN + lane], g);
        g = fmaxf(g, 0.f);
        out[(size_t)q * FIN + lane] = g;
    }
    float d = 0.f;
    if (lane < FIN) {
        float t = g - y[(size_t)q * FIN + lane];
        d = t * t;
    }
#pragma unroll
    for (int off = 32; off; off >>= 1) d += __shfl_xor(d, off);
    if (lane == 0) msep[wid] = d;
    __syncthreads();
    if (threadIdx.x == 0)
        partials[blockIdx.x] = msep[0] + msep[1] + msep[2] + msep[3];
}

// ---------------- phase 2 (fast): exact fp32 weights over survivors; self explicit ----------------
__global__ __launch_bounds__(256) void gather_kernel(const float* __restrict__ x,
                                                     const float* __restrict__ noise,
                                                     const float* __restrict__ y,
                                                     const float* __restrict__ W1,
                                                     const float* __restrict__ b1,
                                                     const int* __restrict__ cnt,
                                                     const int* __restrict__ lists,
                                                     float* __restrict__ out,
                                                     float* __restrict__ partials) {
    __shared__ float e_lds[4][2 * FF];
    __shared__ float msep[4];
    int wid = threadIdx.x >> 6, lane = threadIdx.x & 63;
    int q = blockIdx.x * 4 + wid;
    int bb = q >> 12;
    int nloc = q & (NN - 1);
    size_t base = (size_t)bb * NN;

    float fnd = 0.f;
    if (lane < FIN)          fnd = x[(size_t)q * FIN + lane];
    else if (lane == FF - 1) fnd = noise[q];

    int c = cnt[q];
    if (c > CAP) c = CAP;
    int mj = (lane < c) ? lists[(size_t)q * CAP + lane] : INF_IDX;
    if (mj == nloc) mj = INF_IDX;   // self handled explicitly

    float den = 1.f, num = 0.f;     // self: w=1 (s==0 exactly), diff==0
    for (int it = 0; it < c; ++it) {
        int v = mj;                 // extract smallest remaining index (deterministic order)
#pragma unroll
        for (int off = 32; off; off >>= 1) {
            int o = __shfl_xor(v, off);
            v = v < o ? v : o;
        }
        if (v == INF_IDX) break;
        if (mj == v) mj = INF_IDX;
        int m = v;
        float fmd = 0.f;
        if (lane < FIN)          fmd = x[(base + m) * (size_t)FIN + lane];
        else if (lane == FF - 1) fmd = noise[base + m];
        float diff = (lane < FF) ? (fmd - fnd) : 0.f;
        float s = diff * diff;
#pragma unroll
        for (int off = 32; off; off >>= 1) s += __shfl_xor(s, off);
        float w = __expf(-s);       // exact fp32 d2: any false survivor -> w ~ 0
        den += w;
        num += w * diff;
    }
    float md = num / den;           // den >= 1 always

    head_epilogue(wid, lane, q, fnd, md, y, W1, b1, out, partials, e_lds, msep);
}

// ---------------- phase 2 (fallback, ws too small): brute-force exact scan ----------------
__global__ __launch_bounds__(256) void gather_brute(const float* __restrict__ x,
                                                    const float* __restrict__ noise,
                                                    const float* __restrict__ y,
                                                    const float* __restrict__ W1,
                                                    const float* __restrict__ b1,
                                                    float* __restrict__ out,
                                                    float* __restrict__ partials) {
    __shared__ float e_lds[4][2 * FF];
    __shared__ float msep[4];
    int wid = threadIdx.x >> 6, lane = threadIdx.x & 63;
    int q = blockIdx.x * 4 + wid;
    int bb = q >> 12;
    int nloc = q & (NN - 1);
    size_t base = (size_t)bb * NN;

    float fnd = 0.f;
    if (lane < FIN)          fnd = x[(size_t)q * FIN + lane];
    else if (lane == FF - 1) fnd = noise[q];

    float den = 1.f, num = 0.f;
    for (int m = 0; m < NN; ++m) {
        if (m == nloc) continue;
        float fmd = 0.f;
        if (lane < FIN)          fmd = x[(base + m) * (size_t)FIN + lane];
        else if (lane == FF - 1) fmd = noise[base + m];
        float diff = (lane < FF) ? (fmd - fnd) : 0.f;
        float s = diff * diff;
#pragma unroll
        for (int off = 32; off; off >>= 1) s += __shfl_xor(s, off);
        float w = __expf(-s);
        den += w;
        num += w * diff;
    }
    float md = num / den;

    head_epilogue(wid, lane, q, fnd, md, y, W1, b1, out, partials, e_lds, msep);
}

// ---------------- final: gen_mse (vectorized) ----------------
__global__ __launch_bounds__(256) void reduce_kernel(const float* __restrict__ partials,
                                                     float* __restrict__ out) {
    __shared__ float sw[4];
    int wid = threadIdx.x >> 6, lane = threadIdx.x & 63;
    const float4* p4 = (const float4*)partials;
    float ax = 0.f, ay = 0.f, az = 0.f, aw = 0.f;
#pragma unroll
    for (int i = threadIdx.x; i < (NQ / 4) / 4; i += 256) {
        float4 v = p4[i];
        ax += v.x; ay += v.y; az += v.z; aw += v.w;
    }
    float a = (ax + ay) + (az + aw);
#pragma unroll
    for (int off = 32; off; off >>= 1) a += __shfl_xor(a, off);
    if (lane == 0) sw[wid] = a;
    __syncthreads();
    if (threadIdx.x == 0)
        out[(size_t)NQ * FIN] = (sw[0] + sw[1] + sw[2] + sw[3]) / (float)((size_t)NQ * FIN);
}

extern "C" void kernel_launch(void* const* d_in, const int* in_sizes, int n_in,
                              void* d_out, int out_size, void* d_ws, size_t ws_size,
                              hipStream_t stream) {
    const float* x     = (const float*)d_in[0];
    const float* noise = (const float*)d_in[1];
    const float* y     = (const float*)d_in[2];
    const float* W1    = (const float*)d_in[3];
    const float* b1    = (const float*)d_in[4];
    float* out = (float*)d_out;
    char* ws = (char*)d_ws;

    if (ws_size >= WS_NEED) {
        unsigned short* fbA = (unsigned short*)(ws + OFF_FBA);
        unsigned short* fbB = (unsigned short*)(ws + OFF_FBB);
        int*   cnt     = (int*)(ws + OFF_CNT);
        int*   lists   = (int*)(ws + OFF_LISTS);
        float* partial = (float*)(ws + OFF_PART);

        prep_kernel<<<NQ / 64, 64, 0, stream>>>(x, noise, fbA, fbB, cnt);
        knn_kernel<<<BB * NTRI * 2, 256, 0, stream>>>(fbA, fbB, cnt, lists);
        gather_kernel<<<NQ / 4, 256, 0, stream>>>(x, noise, y, W1, b1, cnt, lists, out, partial);
        reduce_kernel<<<1, 256, 0, stream>>>(partial, out);
    } else {
        // brute-force exact path: needs only 32 KB of scratch for MSE partials
        float* partial = (float*)ws;
        gather_brute<<<NQ / 4, 256, 0, stream>>>(x, noise, y, W1, b1, out, partial);
        reduce_kernel<<<1, 256, 0, stream>>>(partial, out);
    }
}

// Round 6
// 115.799 us; speedup vs baseline: 1.2885x; 1.1944x over previous
//
#include <hip/hip_runtime.h>
#include <hip/hip_bf16.h>
#include <stdint.h>

#define BB   8
#define NN   4096
#define FIN  32
#define FF   33          // FIN + 1 noise channel
#define KPAD 64          // feature dim padded; dims 33,34 carry the threshold fold
#define NQ   (BB*NN)     // 32768 query points
#define CAP  16
#define NTRI 136         // 16*17/2 slab pairs (qt <= ms), 256-row q-slabs
#define INF_IDX 0x7FFFFFFF

// Augmentation: fbA[33]=6.75-sq/2, fbA[34]=1 ; fbB[33]=1, fbB[34]=6.75-sq/2
// => acc = dot - 0.5*sq_n - 0.5*sq_m + 13.5 ;  acc > 0  <=>  d2 < 27

// workspace layout (bytes) — fast path, ~10.2 MB total
#define OFF_FBA    0ull
#define OFF_FBB    (OFF_FBA + (size_t)NQ*KPAD*2)      // 4 MB
#define OFF_CNT    (OFF_FBB + (size_t)NQ*KPAD*2)      // +4 MB
#define OFF_LISTS  (OFF_CNT  + (size_t)NQ*4)
#define OFF_PART   (OFF_LISTS + (size_t)NQ*CAP*4)     // +2 MB
#define WS_NEED    (OFF_PART + (size_t)(NQ/4)*4)

typedef short short8 __attribute__((ext_vector_type(8)));
typedef float floatx4 __attribute__((ext_vector_type(4)));

// ---------------- prep: f=[x,noise] -> two augmented bf16 arrays; zero cnt ----------------
__global__ __launch_bounds__(64) void prep_kernel(const float* __restrict__ x,
                                                  const float* __restrict__ noise,
                                                  unsigned short* __restrict__ fbA,
                                                  unsigned short* __restrict__ fbB,
                                                  int* __restrict__ cnt) {
    int q = blockIdx.x * 64 + threadIdx.x;
    cnt[q] = 0;
    const float4* xr = (const float4*)(x + (size_t)q * FIN);
    float v[FF];
#pragma unroll
    for (int i = 0; i < 8; ++i) {
        float4 t = xr[i];
        v[i*4+0] = t.x; v[i*4+1] = t.y; v[i*4+2] = t.z; v[i*4+3] = t.w;
    }
    v[32] = noise[q];
    float s = 0.f;
#pragma unroll
    for (int d = 0; d < FF; ++d) s += v[d] * v[d];
    unsigned short rowA[KPAD], rowB[KPAD];
#pragma unroll
    for (int d = 0; d < FF; ++d) {
        __hip_bfloat16 h = __float2bfloat16(v[d]);
        unsigned short u = *(unsigned short*)&h;
        rowA[d] = u; rowB[d] = u;
    }
    __hip_bfloat16 hs = __float2bfloat16(6.75f - 0.5f * s);
    unsigned short us = *(unsigned short*)&hs;
    const unsigned short one = 0x3F80;   // bf16 1.0
    rowA[33] = us;  rowA[34] = one;
    rowB[33] = one; rowB[34] = us;
#pragma unroll
    for (int d = 35; d < KPAD; ++d) { rowA[d] = 0; rowB[d] = 0; }
    uint4* dA = (uint4*)(fbA + (size_t)q * KPAD);
    uint4* dB = (uint4*)(fbB + (size_t)q * KPAD);
#pragma unroll
    for (int i = 0; i < 8; ++i) { dA[i] = ((const uint4*)rowA)[i]; dB[i] = ((const uint4*)rowB)[i]; }
}

// ---------------- phase 1: symmetric MFMA sieve, barrier-free, register-prefetched ----------------
// Triangle block (bb, qt<=ms, msub): q-slab = 256 rows, m-range = 128 rows (8 tiles of 16).
// Wave w owns 64 q rows (4 A-tiles), loops m-tiles with next-tile register prefetch.
// Hit iff acc>0 (threshold folded into dims 33/34); recorded for BOTH n and m (m>n once).
// NOTE: launch_bounds min-waves relaxed 6->4: the 6-wave cap forced VGPR=40 and the
// compiler spilled the A-fragments to scratch (129 MB/dispatch of spill traffic, r5).
__global__ __launch_bounds__(256, 4) void knn_kernel(const unsigned short* __restrict__ fbA,
                                                     const unsigned short* __restrict__ fbB,
                                                     int* __restrict__ cnt,
                                                     int* __restrict__ lists) {
    const int bpb = NTRI * 2;            // 272 blocks per batch
    int bb  = blockIdx.x / bpb;
    int rem = blockIdx.x % bpb;
    int tri = rem >> 1, msub = rem & 1;
    int t = tri, qt = 0;
    while (t >= 16 - qt) { t -= 16 - qt; ++qt; }
    int ms = qt + t;

    int wid = threadIdx.x >> 6, lane = threadIdx.x & 63;
    int qb  = qt * 256 + wid * 64;       // wave's query base (batch-local)
    int g16 = lane >> 4, l16 = lane & 15;
    size_t base = (size_t)bb * NN;
    int mstart = ms * 256 + msub * 128;

    // A fragments: 4 tiles of 16 q-rows (held for all 8 m-tiles)
    short8 a0[4], a1[4];
#pragma unroll
    for (int a = 0; a < 4; ++a) {
        const short8* pA = (const short8*)fbA + ((base + qb + a * 16 + l16) * 8 + g16);
        a0[a] = pA[0];
        a1[a] = pA[4];   // k += 32
    }

    const short8* pB = (const short8*)fbB + ((base + mstart + l16) * 8 + g16);
    short8 b0 = pB[0], b1 = pB[4];       // tile 0

    for (int mt = 0; mt < 8; ++mt) {
        short8 n0, n1;
        if (mt < 7) {                    // issue next-tile loads before current compute
            n0 = pB[(mt + 1) * 128];
            n1 = pB[(mt + 1) * 128 + 4];
        }
        int mb = mstart + mt * 16;
        if (mb + 16 > qb) {              // skip tiles fully below the wave's diagonal
            int m = mb + l16;
#pragma unroll
            for (int a = 0; a < 4; ++a) {
                floatx4 acc = {0.f, 0.f, 0.f, 0.f};
                acc = __builtin_amdgcn_mfma_f32_16x16x32_bf16(a0[a], b0, acc, 0, 0, 0);
                acc = __builtin_amdgcn_mfma_f32_16x16x32_bf16(a1[a], b1, acc, 0, 0, 0);
                float mm = fmaxf(fmaxf(acc[0], acc[1]), fmaxf(acc[2], acc[3]));
                if (mm > 0.f) {
#pragma unroll
                    for (int r = 0; r < 4; ++r) {
                        int n = qb + a * 16 + g16 * 4 + r;   // C/D row = (lane>>4)*4 + reg
                        if (acc[r] > 0.f && m > n) {
                            int p1 = atomicAdd(&cnt[base + n], 1);
                            if (p1 < CAP) lists[(base + n) * CAP + p1] = m;
                            int p2 = atomicAdd(&cnt[base + m], 1);
                            if (p2 < CAP) lists[(base + m) * CAP + p2] = n;
                        }
                    }
                }
            }
        }
        b0 = n0; b1 = n1;                // rotate prefetch (dead on last iter)
    }
}

// ---------------- shared head: [f, md] @ W1 + b1, relu, out, mse partial ----------------
__device__ inline void head_epilogue(int wid, int lane, int q, float fnd, float md,
                                     const float* __restrict__ y,
                                     const float* __restrict__ W1,
                                     const float* __restrict__ b1,
                                     float* __restrict__ out,
                                     float* __restrict__ partials,
                                     float (*e_lds)[2 * FF], float* msep) {
    if (lane < FF) {
        e_lds[wid][lane]      = fnd;
        e_lds[wid][FF + lane] = md;
    }
    __syncthreads();
    float g = 0.f;
    if (lane < FIN) {
        g = b1[lane];
#pragma unroll
        for (int e = 0; e < 2 * FF; ++e)
            g = fmaf(e_lds[wid][e], W1[e * FIN + lane], g);
        g = fmaxf(g, 0.f);
        out[(size_t)q * FIN + lane] = g;
    }
    float d = 0.f;
    if (lane < FIN) {
        float t = g - y[(size_t)q * FIN + lane];
        d = t * t;
    }
#pragma unroll
    for (int off = 32; off; off >>= 1) d += __shfl_xor(d, off);
    if (lane == 0) msep[wid] = d;
    __syncthreads();
    if (threadIdx.x == 0)
        partials[blockIdx.x] = msep[0] + msep[1] + msep[2] + msep[3];
}

// ---------------- phase 2 (fast): exact fp32 weights over survivors; self explicit ----------------
__global__ __launch_bounds__(256) void gather_kernel(const float* __restrict__ x,
                                                     const float* __restrict__ noise,
                                                     const float* __restrict__ y,
                                                     const float* __restrict__ W1,
                                                     const float* __restrict__ b1,
                                                     const int* __restrict__ cnt,
                                                     const int* __restrict__ lists,
                                                     float* __restrict__ out,
                                                     float* __restrict__ partials) {
    __shared__ float e_lds[4][2 * FF];
    __shared__ float msep[4];
    int wid = threadIdx.x >> 6, lane = threadIdx.x & 63;
    int q = blockIdx.x * 4 + wid;
    int bb = q >> 12;
    int nloc = q & (NN - 1);
    size_t base = (size_t)bb * NN;

    float fnd = 0.f;
    if (lane < FIN)          fnd = x[(size_t)q * FIN + lane];
    else if (lane == FF - 1) fnd = noise[q];

    int c = cnt[q];
    if (c > CAP) c = CAP;
    int mj = (lane < c) ? lists[(size_t)q * CAP + lane] : INF_IDX;
    if (mj == nloc) mj = INF_IDX;   // self handled explicitly

    float den = 1.f, num = 0.f;     // self: w=1 (s==0 exactly), diff==0
    for (int it = 0; it < c; ++it) {
        int v = mj;                 // extract smallest remaining index (deterministic order)
#pragma unroll
        for (int off = 32; off; off >>= 1) {
            int o = __shfl_xor(v, off);
            v = v < o ? v : o;
        }
        if (v == INF_IDX) break;
        if (mj == v) mj = INF_IDX;
        int m = v;
        float fmd = 0.f;
        if (lane < FIN)          fmd = x[(base + m) * (size_t)FIN + lane];
        else if (lane == FF - 1) fmd = noise[base + m];
        float diff = (lane < FF) ? (fmd - fnd) : 0.f;
        float s = diff * diff;
#pragma unroll
        for (int off = 32; off; off >>= 1) s += __shfl_xor(s, off);
        float w = __expf(-s);       // exact fp32 d2: any false survivor -> w ~ 0
        den += w;
        num += w * diff;
    }
    float md = num / den;           // den >= 1 always

    head_epilogue(wid, lane, q, fnd, md, y, W1, b1, out, partials, e_lds, msep);
}

// ---------------- phase 2 (fallback, ws too small): brute-force exact scan ----------------
__global__ __launch_bounds__(256) void gather_brute(const float* __restrict__ x,
                                                    const float* __restrict__ noise,
                                                    const float* __restrict__ y,
                                                    const float* __restrict__ W1,
                                                    const float* __restrict__ b1,
                                                    float* __restrict__ out,
                                                    float* __restrict__ partials) {
    __shared__ float e_lds[4][2 * FF];
    __shared__ float msep[4];
    int wid = threadIdx.x >> 6, lane = threadIdx.x & 63;
    int q = blockIdx.x * 4 + wid;
    int bb = q >> 12;
    int nloc = q & (NN - 1);
    size_t base = (size_t)bb * NN;

    float fnd = 0.f;
    if (lane < FIN)          fnd = x[(size_t)q * FIN + lane];
    else if (lane == FF - 1) fnd = noise[q];

    float den = 1.f, num = 0.f;
    for (int m = 0; m < NN; ++m) {
        if (m == nloc) continue;
        float fmd = 0.f;
        if (lane < FIN)          fmd = x[(base + m) * (size_t)FIN + lane];
        else if (lane == FF - 1) fmd = noise[base + m];
        float diff = (lane < FF) ? (fmd - fnd) : 0.f;
        float s = diff * diff;
#pragma unroll
        for (int off = 32; off; off >>= 1) s += __shfl_xor(s, off);
        float w = __expf(-s);
        den += w;
        num += w * diff;
    }
    float md = num / den;

    head_epilogue(wid, lane, q, fnd, md, y, W1, b1, out, partials, e_lds, msep);
}

// ---------------- final: gen_mse (vectorized) ----------------
__global__ __launch_bounds__(256) void reduce_kernel(const float* __restrict__ partials,
                                                     float* __restrict__ out) {
    __shared__ float sw[4];
    int wid = threadIdx.x >> 6, lane = threadIdx.x & 63;
    const float4* p4 = (const float4*)partials;
    float ax = 0.f, ay = 0.f, az = 0.f, aw = 0.f;
#pragma unroll
    for (int i = threadIdx.x; i < (NQ / 4) / 4; i += 256) {
        float4 v = p4[i];
        ax += v.x; ay += v.y; az += v.z; aw += v.w;
    }
    float a = (ax + ay) + (az + aw);
#pragma unroll
    for (int off = 32; off; off >>= 1) a += __shfl_xor(a, off);
    if (lane == 0) sw[wid] = a;
    __syncthreads();
    if (threadIdx.x == 0)
        out[(size_t)NQ * FIN] = (sw[0] + sw[1] + sw[2] + sw[3]) / (float)((size_t)NQ * FIN);
}

extern "C" void kernel_launch(void* const* d_in, const int* in_sizes, int n_in,
                              void* d_out, int out_size, void* d_ws, size_t ws_size,
                              hipStream_t stream) {
    const float* x     = (const float*)d_in[0];
    const float* noise = (const float*)d_in[1];
    const float* y     = (const float*)d_in[2];
    const float* W1    = (const float*)d_in[3];
    const float* b1    = (const float*)d_in[4];
    float* out = (float*)d_out;
    char* ws = (char*)d_ws;

    if (ws_size >= WS_NEED) {
        unsigned short* fbA = (unsigned short*)(ws + OFF_FBA);
        unsigned short* fbB = (unsigned short*)(ws + OFF_FBB);
        int*   cnt     = (int*)(ws + OFF_CNT);
        int*   lists   = (int*)(ws + OFF_LISTS);
        float* partial = (float*)(ws + OFF_PART);

        prep_kernel<<<NQ / 64, 64, 0, stream>>>(x, noise, fbA, fbB, cnt);
        knn_kernel<<<BB * NTRI * 2, 256, 0, stream>>>(fbA, fbB, cnt, lists);
        gather_kernel<<<NQ / 4, 256, 0, stream>>>(x, noise, y, W1, b1, cnt, lists, out, partial);
        reduce_kernel<<<1, 256, 0, stream>>>(partial, out);
    } else {
        // brute-force exact path: needs only 32 KB of scratch for MSE partials
        float* partial = (float*)ws;
        gather_brute<<<NQ / 4, 256, 0, stream>>>(x, noise, y, W1, b1, out, partial);
        reduce_kernel<<<1, 256, 0, stream>>>(partial, out);
    }
}